// Round 13
// baseline (703.151 us; speedup 1.0000x reference)
//
#include <hip/hip_runtime.h>
#include <hip/hip_bf16.h>
#include <stdint.h>

#define DI __device__ __forceinline__

typedef __bf16 bf16x8 __attribute__((ext_vector_type(8)));
typedef __bf16 bf16x4 __attribute__((ext_vector_type(4)));
typedef float f32x16 __attribute__((ext_vector_type(16)));
typedef float f32x4 __attribute__((ext_vector_type(4)));

DI float bf2f(unsigned short u){ return __uint_as_float(((unsigned int)u)<<16); }
DI unsigned short f2bf(float f){
  unsigned int x = __float_as_uint(f);
  x += 0x7fffu + ((x>>16)&1u);           // RNE; inputs are finite
  return (unsigned short)(x>>16);
}
DI float sigmoidf_(float x){ return 1.0f/(1.0f + __expf(-x)); }
DI float tanhf_(float x){ return 2.0f/(1.0f + __expf(-2.0f*x)) - 1.0f; }  // NaN-safe at both extremes

DI void gld_lds16(const void* g, void* l){
  __builtin_amdgcn_global_load_lds((const __attribute__((address_space(1))) void*)g,
                                   (__attribute__((address_space(3))) void*)l, 16, 0, 0);
}
DI f32x16 mfma32(bf16x8 a, bf16x8 b, f32x16 c){
  return __builtin_amdgcn_mfma_f32_32x32x16_bf16(a, b, c, 0, 0, 0);
}
DI f32x4 mfma16(bf16x8 a, bf16x8 b, f32x4 c){
  return __builtin_amdgcn_mfma_f32_16x16x32_bf16(a, b, c, 0, 0, 0);
}

// ============ merged weight prep: all packs in ONE kernel ============
// 32x32 frag: col n=(l&31)+32*nt, k=(l>>5)*8+j ; 16x16 frag: row/col=l&15, k=(l>>4)*8+j
__global__ __launch_bounds__(256) void k_prep_all(
    const float* __restrict__ w1, const float* __restrict__ w2, const float* __restrict__ w3,
    const float* __restrict__ fcw, const float* __restrict__ wih,
    const float* __restrict__ whh, const float* __restrict__ bih, const float* __restrict__ bhh,
    unsigned short* __restrict__ W1P, unsigned short* __restrict__ W2P,
    unsigned short* __restrict__ W3P, unsigned short* __restrict__ FCWP,
    unsigned short* __restrict__ GXWP, unsigned short* __restrict__ WHHP,
    float* __restrict__ GXB)
{
  const int blk = blockIdx.x, tid = threadIdx.x;
  if (blk < 8){                                        // conv1: 2048 = 4 kk * 512, /255 folded
    int idx = blk*256 + tid;
    int j=idx&7, l=(idx>>3)&63, kk=idx>>9;
    int oc=l&31, kg=kk*16+((l>>5)<<3)+j;
    W1P[idx] = f2bf(w1[oc*64 + kg] * (1.0f/255.0f));
  } else if (blk < 136){                               // conv2: 32768 = 16 s * 2 kh * 2 nt * 512
    int idx = (blk-8)*256 + tid;
    int j=idx&7, l=(idx>>3)&63, nt=(idx>>9)&1, kh=(idx>>10)&1, s=idx>>11;
    int oc=nt*32+(l&31), ic=kh*16+(l>>5)*8+j, ky=s>>2, kx=s&3;
    W2P[idx] = f2bf(w2[((oc*32+ic)*4+ky)*4+kx]);
  } else if (blk < 280){                               // conv3: 36864 = 9 s * 4 kh * 2 nt * 512
    int idx = (blk-136)*256 + tid;
    int j=idx&7, l=(idx>>3)&63, nt=(idx>>9)&1, kh=(idx>>10)&3, s=idx>>12;
    int oc=nt*32+(l&31), ic=kh*16+(l>>5)*8+j, ky=s/3, kx=s-ky*3;
    W3P[idx] = f2bf(w3[((oc*64+ic)*3+ky)*3+kx]);
  } else if (blk < 6552){                              // FC: 1605632 items; A3 k'=pos*64+c
    int i = (blk-280)*256 + tid;
    int t2 = i&511, rest = i>>9;
    int ks = rest%196, nt = rest/196;
    int j=t2&7, l=t2>>3;
    int n=nt*32+(l&31), k=ks*16+(l>>5)*8+j;
    int c=k&63, pos=k>>6;
    float wv = fcw[(size_t)n*3136 + c*49 + pos];
    unsigned short hi = f2bf(wv);
    FCWP[i] = hi;
    FCWP[1605632 + i] = f2bf(wv - bf2f(hi));
  } else if (blk < 7320){                              // GX: 196608 items, hi+lo
    int i = (blk-6552)*256 + tid;
    int t2 = i&511, rest = i>>9;
    int ks = rest&31, nt = rest>>5;
    int j=t2&7, l=t2>>3;
    int n=nt*32+(l&31), k=ks*16+(l>>5)*8+j;
    float wv = wih[(size_t)n*512 + k];
    unsigned short hi = f2bf(wv);
    GXWP[i] = hi;
    GXWP[196608 + i] = f2bf(wv - bf2f(hi));
  } else if (blk < 7512){                              // WHH 16x16 A-frags: 49152 items
    int i = (blk-7320)*256 + tid;                      // i = ((g*8+v)*4+kf)*512 + l*8 + j
    int j=i&7, l=(i>>3)&63, kf=(i>>9)&3, v=(i>>11)&7, g=i>>14;
    int m = g*128 + v*16 + (l&15);                     // gate-unit row of whh
    int k = kf*32 + ((l>>4)<<3) + j;
    WHHP[i] = f2bf(whh[(size_t)m*128 + k]);
  } else {                                             // GX bias fold: bih + bhh (r,z only)
    int i = (blk-7512)*256 + tid;
    if (i < 384) GXB[i] = bih[i] + (i < 256 ? bhh[i] : 0.0f);
  }
}

// ============ conv1 (MFMA): x[.,1,84,84] -> 8x8 s4 + relu -> A1[nloc][400 pos][32 ic] bf16
__global__ __launch_bounds__(256) void k_conv1(const float* __restrict__ x,
    const unsigned short* __restrict__ w1p, const float* __restrict__ b,
    unsigned short* __restrict__ a1, int nbase)
{
  __shared__ __align__(16) char imgs[4*14784];     // 4 x [84 rows][88 cols] bf16
  const int tid=threadIdx.x, l=tid&63, w=tid>>6;
  const int nloc = blockIdx.x*4 + w;
  char* myimg = imgs + w*14784;
  const float* xp = x + (size_t)(nbase+nloc)*7056;

  for (int it=0; it<28; ++it){
    int idx4 = l + it*64;                          // over 1764 float4s
    if (idx4 < 1764){
      float4 v = *(const float4*)(xp + idx4*4);
      int row = idx4/21, rem = idx4 - row*21;
      ushort4 u; u.x=f2bf(v.x); u.y=f2bf(v.y); u.z=f2bf(v.z); u.w=f2bf(v.w);
      *(ushort4*)(myimg + row*176 + rem*8) = u;
    }
  }

  bf16x8 wb[4];
  #pragma unroll
  for (int kk=0;kk<4;kk++) wb[kk] = *(const bf16x8*)(w1p + (kk*64 + l)*8);
  const float bias = b[l&31];
  asm volatile("s_waitcnt lgkmcnt(0)" ::: "memory");   // staging ds_writes drained

  const int kyh = (l>>5);
  unsigned short* obase = a1 + (size_t)nloc*12800;
  for (int mt=0; mt<13; ++mt){
    int p = mt*32 + (l&31);
    p = min(p, 399);
    const int oy = p/20, ox = p - oy*20;
    const int rbyte = oy*4*176 + ox*8;
    f32x16 acc = {};
    #pragma unroll
    for (int kk=0;kk<4;kk++){
      const int a = rbyte + (kk*2 + kyh)*176;
      bf16x8 af;
      *(bf16x4*)&af       = *(const bf16x4*)(myimg + a);
      *((bf16x4*)&af + 1) = *(const bf16x4*)(myimg + a + 8);
      acc = mfma32(af, wb[kk], acc);
    }
    const int oc = l&31;
    #pragma unroll
    for (int rg=0;rg<16;rg++){
      int row = (rg&3) + 8*(rg>>2) + 4*kyh;
      int pos = mt*32 + row;
      if (pos < 400)
        obase[pos*32 + oc] = f2bf(fmaxf(acc[rg] + bias, 0.f));
    }
  }
}

// ============ conv2: A1[nloc][400][32] -> 4x4 s2 + relu -> A2[nbase+nloc][81][64] (MFMA)
__global__ __launch_bounds__(256) void k_conv2(const unsigned short* __restrict__ a1,
    const unsigned short* __restrict__ w2p, const float* __restrict__ b2,
    unsigned short* __restrict__ a2, int nbase)
{
  extern __shared__ __align__(16) char smem[];   // 4*25600
  const int tid=threadIdx.x, l=tid&63, w=tid>>6;
  const int nloc = blockIdx.x*4 + w;
  char* myimg = smem + w*25600;
  const char* gimg = (const char*)(a1 + (size_t)nloc*12800);
  #pragma unroll
  for (int i=0;i<25;i++){
    int o = i*1024 + l*16;
    int q = o ^ (((o>>7)&7)<<4);
    gld_lds16(gimg + q, myimg + i*1024);
  }
  __syncthreads();
  int rbase[3];
  #pragma unroll
  for (int mt=0;mt<3;mt++){
    int r = mt*32 + (l&31);
    int oy=r/9, ox=r-oy*9;
    rbase[mt] = 40*oy + 2*ox;
  }
  const int grp16 = (l>>5)*16;
  f32x16 acc[3][2] = {};
  #pragma unroll
  for (int ky=0;ky<4;ky++){
    #pragma unroll
    for (int kx=0;kx<4;kx++){
      const int s = ky*4+kx;
      #pragma unroll
      for (int kh=0;kh<2;kh++){
        bf16x8 b0 = *(const bf16x8*)(w2p + (((s*2+kh)*2+0)*64 + l)*8);
        bf16x8 b1 = *(const bf16x8*)(w2p + (((s*2+kh)*2+1)*64 + l)*8);
        #pragma unroll
        for (int mt=0;mt<3;mt++){
          int ip = rbase[mt] + ky*20 + kx;
          ip = min(ip, 399);
          int byte = (ip*64 + kh*32 + grp16) ^ (((ip>>1)&7)<<4);
          bf16x8 af = *(const bf16x8*)(myimg + byte);
          acc[mt][0] = mfma32(af, b0, acc[mt][0]);
          acc[mt][1] = mfma32(af, b1, acc[mt][1]);
        }
      }
    }
  }
  const float bias0 = b2[l&31], bias1 = b2[32+(l&31)];
  unsigned short* ob = (unsigned short*)myimg;
  #pragma unroll
  for (int mt=0;mt<3;mt++){
    #pragma unroll
    for (int rg=0;rg<16;rg++){
      int r = mt*32 + (rg&3) + 8*(rg>>2) + 4*(l>>5);
      ob[r*64 + (l&31)]      = f2bf(fmaxf(acc[mt][0][rg]+bias0,0.f));
      ob[r*64 + 32 + (l&31)] = f2bf(fmaxf(acc[mt][1][rg]+bias1,0.f));
    }
  }
  asm volatile("s_waitcnt lgkmcnt(0)" ::: "memory");
  const uint4* s4 = (const uint4*)ob;
  uint4* d4 = (uint4*)(a2 + (size_t)(nbase+nloc)*5184);
  #pragma unroll
  for (int i=0;i<11;i++){
    int c = i*64 + l;
    if (c < 648) d4[c] = s4[c];
  }
}

// ============ conv3: A2[n][81][64] -> 3x3 s1 + relu -> A3[n][49][64] bf16 (MFMA)
__global__ __launch_bounds__(256) void k_conv3(const unsigned short* __restrict__ a2,
    const unsigned short* __restrict__ w3p, const float* __restrict__ b3,
    unsigned short* __restrict__ a3)
{
  __shared__ __align__(16) char smem3[4*11264];
  const int tid=threadIdx.x, l=tid&63, w=tid>>6;
  const int n = blockIdx.x*4 + w;
  char* myimg = smem3 + w*11264;
  const char* gimg = (const char*)(a2 + (size_t)n*5184);
  #pragma unroll
  for (int i=0;i<11;i++){
    int c = i*64 + l;
    int cc = min(c, 647);
    int o = cc*16;
    int q = o ^ (((o>>7)&7)<<4);
    gld_lds16(gimg + q, myimg + i*1024);
  }
  __syncthreads();
  int base[2];
  #pragma unroll
  for (int mt=0;mt<2;mt++){
    int r = mt*32 + (l&31);
    int oy=r/7, ox=r-oy*7;
    base[mt] = oy*9 + ox;
  }
  const int grp16 = (l>>5)*16;
  f32x16 acc[2][2] = {};
  #pragma unroll
  for (int ky=0;ky<3;ky++){
    #pragma unroll
    for (int kx=0;kx<3;kx++){
      const int s = ky*3+kx;
      #pragma unroll
      for (int kh=0;kh<4;kh++){
        bf16x8 b0 = *(const bf16x8*)(w3p + (((s*4+kh)*2+0)*64 + l)*8);
        bf16x8 b1 = *(const bf16x8*)(w3p + (((s*4+kh)*2+1)*64 + l)*8);
        #pragma unroll
        for (int mt=0;mt<2;mt++){
          int ip = min(base[mt] + ky*9 + kx, 80);
          int byte = (ip*128 + kh*32 + grp16) ^ ((ip&7)<<4);
          bf16x8 af = *(const bf16x8*)(myimg + byte);
          acc[mt][0] = mfma32(af, b0, acc[mt][0]);
          acc[mt][1] = mfma32(af, b1, acc[mt][1]);
        }
      }
    }
  }
  const float bias0 = b3[l&31], bias1 = b3[32+(l&31)];
  unsigned short* ob = (unsigned short*)myimg;
  #pragma unroll
  for (int mt=0;mt<2;mt++){
    #pragma unroll
    for (int rg=0;rg<16;rg++){
      int r = mt*32 + (rg&3) + 8*(rg>>2) + 4*(l>>5);
      if (r < 49){
        ob[r*64 + (l&31)]      = f2bf(fmaxf(acc[mt][0][rg]+bias0,0.f));
        ob[r*64 + 32 + (l&31)] = f2bf(fmaxf(acc[mt][1][rg]+bias1,0.f));
      }
    }
  }
  asm volatile("s_waitcnt lgkmcnt(0)" ::: "memory");
  const uint4* s4 = (const uint4*)ob;
  uint4* d4 = (uint4*)(a3 + (size_t)n*3136);
  #pragma unroll
  for (int i=0;i<7;i++){
    int c = i*64 + l;
    if (c < 392) d4[c] = s4[c];
  }
}

// ============ GEMM: out[M,N] = act(A[M,K](bf16) @ W^frag + bias) ; BM=128 BN=64 BK=32
template<bool RELU, bool OBF16, bool HILO>
__global__ __launch_bounds__(256) void k_gemm(const unsigned short* __restrict__ A, int K,
    const unsigned short* __restrict__ Wp, int loOff, const float* __restrict__ bias,
    void* __restrict__ out, int N)
{
  __shared__ __align__(16) char ab[2][8192];
  const int tid=threadIdx.x, l=tid&63, w=tid>>6;
  const int m0=blockIdx.y*128, n0=blockIdx.x*64;
  const int KS=K>>4, T=K>>5;
  const int mh=w&1, ntl=w>>1;
  const int ntg = blockIdx.x*2 + ntl;
  const char* Ab = (const char*)A;

  f32x16 acc[2] = {};
  bf16x8 bh0, bh1, bl0, bl1, nh0, nh1, nl0, nl1;

  #pragma unroll
  for (int i=0;i<2;i++){
    int o = (w*2+i)*1024 + l*16;
    int q = o ^ (((o>>7)&7)<<4);
    int row = q>>6, kc=(q>>4)&3;
    gld_lds16(Ab + ((size_t)(m0+row)*K)*2 + kc*16, ab[0] + (w*2+i)*1024);
  }
  {
    const unsigned short* p0 = Wp + ((size_t)(ntg*KS)*64 + l)*8;
    bh0 = *(const bf16x8*)(p0);
    bh1 = *(const bf16x8*)(p0 + 512);
    if (HILO){
      bl0 = *(const bf16x8*)(p0 + loOff);
      bl1 = *(const bf16x8*)(p0 + loOff + 512);
    }
  }
  __syncthreads();

  for (int t=0;t<T;t++){
    const int cb = t&1;
    if (t+1 < T){
      #pragma unroll
      for (int i=0;i<2;i++){
        int o = (w*2+i)*1024 + l*16;
        int q = o ^ (((o>>7)&7)<<4);
        int row = q>>6, kc=(q>>4)&3;
        gld_lds16(Ab + ((size_t)(m0+row)*K + (t+1)*32)*2 + kc*16, ab[cb^1] + (w*2+i)*1024);
      }
      const unsigned short* pn = Wp + ((size_t)(ntg*KS + (t+1)*2)*64 + l)*8;
      nh0 = *(const bf16x8*)(pn);
      nh1 = *(const bf16x8*)(pn + 512);
      if (HILO){
        nl0 = *(const bf16x8*)(pn + loOff);
        nl1 = *(const bf16x8*)(pn + loOff + 512);
      }
    }
    #pragma unroll
    for (int mt=0;mt<2;mt++){
      int r = mh*64 + mt*32 + (l&31);
      int b0 = (r*64 + (l>>5)*16) ^ (((r>>1)&7)<<4);
      bf16x8 a0 = *(const bf16x8*)(ab[cb] + b0);
      bf16x8 a1 = *(const bf16x8*)(ab[cb] + (b0^32));
      acc[mt] = mfma32(a0, bh0, acc[mt]);
      acc[mt] = mfma32(a1, bh1, acc[mt]);
      if (HILO){
        acc[mt] = mfma32(a0, bl0, acc[mt]);
        acc[mt] = mfma32(a1, bl1, acc[mt]);
      }
    }
    __syncthreads();
    bh0=nh0; bh1=nh1;
    if (HILO){ bl0=nl0; bl1=nl1; }
  }

  const int col = n0 + ntl*32 + (l&31);
  const float bv = bias[col];
  #pragma unroll
  for (int mt=0;mt<2;mt++){
    #pragma unroll
    for (int rg=0;rg<16;rg++){
      int r = m0 + mh*64 + mt*32 + (rg&3) + 8*(rg>>2) + 4*(l>>5);
      float v = acc[mt][rg] + bv;
      if (RELU) v = fmaxf(v, 0.f);
      if (OBF16) ((unsigned short*)out)[(size_t)r*N + col] = f2bf(v);
      else       ((float*)out)[(size_t)r*N + col] = v;
    }
  }
}

// ============ GRU scan v7: ONE block, 8 waves; wave = unit-block v (0..7).
// Each wave computes its 16 units for ALL 3 gates and BOTH batch-halves:
// 8 ds_read_b128 + 24 mfma16 per step (192 MFMA total = full 384x32 gates).
// hp fp32 in regs (C rows at t == lane's hp at t+1); br/bz folded into gx at prep.
__global__ __launch_bounds__(512) void k_gru_mfma(const float* __restrict__ gx,
    const float* __restrict__ done, const float* __restrict__ h0,
    const unsigned short* __restrict__ whhp, const float* __restrict__ bhh,
    float* __restrict__ hid, float* __restrict__ hfin)
{
  __shared__ __align__(16) char hsb[2*8448];       // 2 x [32 b][132 u] bf16 (264B rows)
  const int tid = threadIdx.x, l = tid&63, v = tid>>6;   // v = wave = unit-block 0..7
  const int bl = l&15;
  const int u0 = v*16 + ((l>>4)<<2);

  bf16x8 wf[12];                                   // A-frags: 3 gates x 4 K-frags
  #pragma unroll
  for (int g=0; g<3; ++g)
    #pragma unroll
    for (int kf=0; kf<4; ++kf)
      wf[g*4+kf] = *(const bf16x8*)(whhp + (size_t)(((g*8+v)*4+kf)*64 + l)*8);

  float bn4[4];
  #pragma unroll
  for (int i=0;i<4;i++) bn4[i] = bhh[256 + u0 + i];

  float hp[2][4];
  #pragma unroll
  for (int h=0; h<2; ++h){
    const int b = h*16 + bl;
    float4 h4 = *(const float4*)(h0 + (size_t)b*128 + u0);
    hp[h][0]=h4.x; hp[h][1]=h4.y; hp[h][2]=h4.z; hp[h][3]=h4.w;
    uint2 pk;
    pk.x = (unsigned)f2bf(h4.x) | ((unsigned)f2bf(h4.y)<<16);
    pk.y = (unsigned)f2bf(h4.z) | ((unsigned)f2bf(h4.w)<<16);
    *(uint2*)(hsb + b*264 + u0*2) = pk;
  }

  // prefetch t=0 gx/done (both halves)
  const float4* gx4 = (const float4*)gx;
  float4 pg[2][3]; float pd[2];
  #pragma unroll
  for (int h=0; h<2; ++h){
    const int b = h*16 + bl;
    const size_t gb = (size_t)b*96 + (u0>>2);
    pg[h][0]=gx4[gb]; pg[h][1]=gx4[gb+32]; pg[h][2]=gx4[gb+64];
    pd[h]=done[b];
  }
  __syncthreads();

  for (int t=0; t<128; ++t){
    const char* hc = hsb + (t&1)*8448;
    char* hnx = hsb + ((t+1)&1)*8448;
    float4 cg[2][3]; float cd[2];
    #pragma unroll
    for (int h=0; h<2; ++h){
      cg[h][0]=pg[h][0]; cg[h][1]=pg[h][1]; cg[h][2]=pg[h][2]; cd[h]=pd[h];
    }
    if (t+1 < 128){
      #pragma unroll
      for (int h=0; h<2; ++h){
        const int b = h*16 + bl;
        const size_t gb = (size_t)((t+1)*32 + b)*96 + (u0>>2);
        pg[h][0]=gx4[gb]; pg[h][1]=gx4[gb+32]; pg[h][2]=gx4[gb+64];
        pd[h]=done[(t+1)*32+b];
      }
    }
    f32x4 acc[2][3] = {};
    #pragma unroll
    for (int h=0; h<2; ++h){
      const int b = h*16 + bl;
      #pragma unroll
      for (int kf=0; kf<4; ++kf){
        bf16x8 hb = *(const bf16x8*)(hc + b*264 + kf*64 + ((l>>4)<<4));
        acc[h][0] = mfma16(wf[kf],   hb, acc[h][0]);
        acc[h][1] = mfma16(wf[4+kf], hb, acc[h][1]);
        acc[h][2] = mfma16(wf[8+kf], hb, acc[h][2]);
      }
    }
    #pragma unroll
    for (int h=0; h<2; ++h){
      const int b = h*16 + bl;
      const float keep = 1.0f - cd[h];
      const float gr[4]={cg[h][0].x,cg[h][0].y,cg[h][0].z,cg[h][0].w};
      const float gz[4]={cg[h][1].x,cg[h][1].y,cg[h][1].z,cg[h][1].w};
      const float gn[4]={cg[h][2].x,cg[h][2].y,cg[h][2].z,cg[h][2].w};
      float hn[4];
      #pragma unroll
      for (int i=0;i<4;i++){
        const float r  = sigmoidf_(gr[i] + keep*acc[h][0][i]);
        const float z  = sigmoidf_(gz[i] + keep*acc[h][1][i]);
        const float nn = tanhf_  (gn[i] + r*(keep*acc[h][2][i] + bn4[i]));
        hn[i] = (1.0f - z)*nn + z*(keep*hp[h][i]);
        hp[h][i] = hn[i];
      }
      *(float4*)(hid + (size_t)(t*32+b)*128 + u0) = float4{hn[0],hn[1],hn[2],hn[3]};
      uint2 pk;
      pk.x = (unsigned)f2bf(hn[0]) | ((unsigned)f2bf(hn[1])<<16);
      pk.y = (unsigned)f2bf(hn[2]) | ((unsigned)f2bf(hn[3])<<16);
      *(uint2*)(hnx + b*264 + u0*2) = pk;
    }
    asm volatile("s_waitcnt lgkmcnt(0)\n\ts_barrier" ::: "memory");
    __builtin_amdgcn_sched_barrier(0);
  }
  #pragma unroll
  for (int h=0; h<2; ++h){
    const int b = h*16 + bl;
    *(float4*)(hfin + (size_t)b*128 + u0) = float4{hp[h][0],hp[h][1],hp[h][2],hp[h][3]};
  }
}

// ============ heads: logits[4096,6], value[4096]
__global__ __launch_bounds__(256) void k_heads(const float* __restrict__ hid,
    const float* __restrict__ aw, const float* __restrict__ ab,
    const float* __restrict__ cw, const float* __restrict__ cb,
    float* __restrict__ out)
{
  __shared__ __align__(16) float wsm[7*128];
  __shared__ float bb[7];
  const int tid = threadIdx.x;
  for (int i=tid;i<896;i+=256) wsm[i] = (i<768) ? aw[i] : cw[i-768];
  if (tid<7) bb[tid] = (tid<6) ? ab[tid] : cb[0];
  __syncthreads();
  const int idx = blockIdx.x*256 + tid;    // < 28672 exactly
  const int n = idx/7, a = idx - n*7;
  const float4* hp = (const float4*)(hid + (size_t)n*128);
  const float4* wp = (const float4*)(&wsm[a*128]);
  float s = bb[a];
  #pragma unroll
  for (int q=0;q<32;q++){
    const float4 h4=hp[q], w4=wp[q];
    s += h4.x*w4.x + h4.y*w4.y + h4.z*w4.z + h4.w*w4.w;
  }
  if (a<6) out[(size_t)n*6+a]=s; else out[24576+n]=s;
}

extern "C" void kernel_launch(void* const* d_in, const int* in_sizes, int n_in,
                              void* d_out, int out_size, void* d_ws, size_t ws_size,
                              hipStream_t stream)
{
  const float* x    = (const float*)d_in[0];
  const float* done = (const float*)d_in[1];
  const float* h0   = (const float*)d_in[2];
  const float* c1w  = (const float*)d_in[3];
  const float* c1b  = (const float*)d_in[4];
  const float* c2w  = (const float*)d_in[5];
  const float* c2b  = (const float*)d_in[6];
  const float* c3w  = (const float*)d_in[7];
  const float* c3b  = (const float*)d_in[8];
  const float* fcw  = (const float*)d_in[9];
  const float* fcb  = (const float*)d_in[10];
  const float* wih  = (const float*)d_in[11];
  const float* whh  = (const float*)d_in[12];
  const float* bih  = (const float*)d_in[13];
  const float* bhh  = (const float*)d_in[14];
  const float* aw   = (const float*)d_in[15];
  const float* ab   = (const float*)d_in[16];
  const float* cw   = (const float*)d_in[17];
  const float* cb   = (const float*)d_in[18];
  float* out = (float*)d_out;
  char* ws = (char*)d_ws;

  // ---- workspace layout (bytes). LIVE-RANGE AUDIT (R12 bug: WHHP/GXB were inside A1):
  //  packs written by prep, read late -> MUST be outside every later-written region.
  //  [0, 7352320)           : W1P/W2P/W3P/FCWP/GXWP (prep -> convs/gemms)   SAFE
  //  [7352320, 59781120)    : A1 (conv1 writes passes 0,1) then A3 [7.3M,33.0M),
  //                           FEAT [33.0M,37.2M), GX [37.2M,43.5M), HID [43.5M,45.6M)
  //                           (all written AFTER A1 dead)
  //  [59781120, 102248448)  : A2
  //  [102248448, 102348288) : WHHP + GXB  <-- moved PAST A2; nothing ever writes here
  unsigned short* W1P  = (unsigned short*)(ws);               // 4096 B
  unsigned short* W2P  = (unsigned short*)(ws + 4096);        // 65536 B
  unsigned short* W3P  = (unsigned short*)(ws + 69632);       // 73728 B
  unsigned short* FCWP = (unsigned short*)(ws + 143360);      // 6422528 B (hi+lo)
  unsigned short* GXWP = (unsigned short*)(ws + 6565888);     // 786432 B (hi+lo)
  unsigned short* A1   = (unsigned short*)(ws + 7352320);
  unsigned short* A2   = (unsigned short*)(ws + 59781120);    // [59781120, 102248448)
  unsigned short* A3   = (unsigned short*)(ws + 7352320);
  unsigned short* FEAT = (unsigned short*)(ws + 33042432);    // 4194304
  float* GX   = (float*)(ws + 37236736);                      // 6291456
  float* HID  = (float*)(ws + 43528192);                      // 2097152
  unsigned short* WHHP = (unsigned short*)(ws + 102248448);   // 98304 B
  float* GXB  = (float*)(ws + 102346752);                     // 1536 B

  static bool attr_set = false;
  if (!attr_set) {
    (void)hipFuncSetAttribute((const void*)k_conv2, hipFuncAttributeMaxDynamicSharedMemorySize, 102400);
    attr_set = true;
  }

  k_prep_all<<<7514, 256, 0, stream>>>(c1w, c2w, c3w, fcw, wih, whh, bih, bhh,
                                       W1P, W2P, W3P, FCWP, GXWP, WHHP, GXB);

  for (int pass=0; pass<2; pass++){
    k_conv1<<<512, 256, 0, stream>>>(x, W1P, c1b, A1, pass*2048);
    k_conv2<<<512, 256, 102400, stream>>>(A1, W2P, c2b, A2, pass*2048);
  }
  k_conv3<<<1024, 256, 0, stream>>>(A2, W3P, c3b, A3);
  k_gemm<true, true, false><<<dim3(8,32), 256, 0, stream>>>(A3, 3136, FCWP, 0, fcb, (void*)FEAT, 512);
  k_gemm<false,false,true ><<<dim3(6,32), 256, 0, stream>>>(FEAT, 512, GXWP, 196608, GXB, (void*)GX, 384);
  k_gru_mfma<<<1, 512, 0, stream>>>(GX, done, h0, WHHP, bhh, HID, out + 28672);
  k_heads<<<112, 256, 0, stream>>>(HID, aw, ab, cw, cb, out);
}

// Round 14
// 678.955 us; speedup vs baseline: 1.0356x; 1.0356x over previous
//
#include <hip/hip_runtime.h>
#include <hip/hip_bf16.h>
#include <stdint.h>

#define DI __device__ __forceinline__

typedef __bf16 bf16x8 __attribute__((ext_vector_type(8)));
typedef __bf16 bf16x4 __attribute__((ext_vector_type(4)));
typedef float f32x16 __attribute__((ext_vector_type(16)));
typedef float f32x4 __attribute__((ext_vector_type(4)));

DI float bf2f(unsigned short u){ return __uint_as_float(((unsigned int)u)<<16); }
DI unsigned short f2bf(float f){
  unsigned int x = __float_as_uint(f);
  x += 0x7fffu + ((x>>16)&1u);           // RNE; inputs are finite
  return (unsigned short)(x>>16);
}
DI float sigmoidf_(float x){ return 1.0f/(1.0f + __expf(-x)); }
DI float tanhf_(float x){ return 2.0f/(1.0f + __expf(-2.0f*x)) - 1.0f; }  // NaN-safe at both extremes

DI void gld_lds16(const void* g, void* l){
  __builtin_amdgcn_global_load_lds((const __attribute__((address_space(1))) void*)g,
                                   (__attribute__((address_space(3))) void*)l, 16, 0, 0);
}
DI f32x16 mfma32(bf16x8 a, bf16x8 b, f32x16 c){
  return __builtin_amdgcn_mfma_f32_32x32x16_bf16(a, b, c, 0, 0, 0);
}
DI f32x4 mfma16(bf16x8 a, bf16x8 b, f32x4 c){
  return __builtin_amdgcn_mfma_f32_16x16x32_bf16(a, b, c, 0, 0, 0);
}

// ============ merged weight prep: all packs in ONE kernel ============
// 32x32 frag: col n=(l&31)+32*nt, k=(l>>5)*8+j ; 16x16 frag: row/col=l&15, k=(l>>4)*8+j
__global__ __launch_bounds__(256) void k_prep_all(
    const float* __restrict__ w1, const float* __restrict__ w2, const float* __restrict__ w3,
    const float* __restrict__ fcw, const float* __restrict__ wih,
    const float* __restrict__ whh, const float* __restrict__ bih, const float* __restrict__ bhh,
    unsigned short* __restrict__ W1P, unsigned short* __restrict__ W2P,
    unsigned short* __restrict__ W3P, unsigned short* __restrict__ FCWP,
    unsigned short* __restrict__ GXWP, unsigned short* __restrict__ WHHP,
    float* __restrict__ GXB)
{
  const int blk = blockIdx.x, tid = threadIdx.x;
  if (blk < 8){                                        // conv1: 2048 = 4 kk * 512, /255 folded
    int idx = blk*256 + tid;
    int j=idx&7, l=(idx>>3)&63, kk=idx>>9;
    int oc=l&31, kg=kk*16+((l>>5)<<3)+j;
    W1P[idx] = f2bf(w1[oc*64 + kg] * (1.0f/255.0f));
  } else if (blk < 136){                               // conv2: 32768 = 16 s * 2 kh * 2 nt * 512
    int idx = (blk-8)*256 + tid;
    int j=idx&7, l=(idx>>3)&63, nt=(idx>>9)&1, kh=(idx>>10)&1, s=idx>>11;
    int oc=nt*32+(l&31), ic=kh*16+(l>>5)*8+j, ky=s>>2, kx=s&3;
    W2P[idx] = f2bf(w2[((oc*32+ic)*4+ky)*4+kx]);
  } else if (blk < 280){                               // conv3: 36864 = 9 s * 4 kh * 2 nt * 512
    int idx = (blk-136)*256 + tid;
    int j=idx&7, l=(idx>>3)&63, nt=(idx>>9)&1, kh=(idx>>10)&3, s=idx>>12;
    int oc=nt*32+(l&31), ic=kh*16+(l>>5)*8+j, ky=s/3, kx=s-ky*3;
    W3P[idx] = f2bf(w3[((oc*64+ic)*3+ky)*3+kx]);
  } else if (blk < 6552){                              // FC: 1605632 items; A3 k'=pos*64+c
    int i = (blk-280)*256 + tid;
    int t2 = i&511, rest = i>>9;
    int ks = rest%196, nt = rest/196;
    int j=t2&7, l=t2>>3;
    int n=nt*32+(l&31), k=ks*16+(l>>5)*8+j;
    int c=k&63, pos=k>>6;
    float wv = fcw[(size_t)n*3136 + c*49 + pos];
    unsigned short hi = f2bf(wv);
    FCWP[i] = hi;
    FCWP[1605632 + i] = f2bf(wv - bf2f(hi));
  } else if (blk < 7320){                              // GX: 196608 items, hi+lo
    int i = (blk-6552)*256 + tid;
    int t2 = i&511, rest = i>>9;
    int ks = rest&31, nt = rest>>5;
    int j=t2&7, l=t2>>3;
    int n=nt*32+(l&31), k=ks*16+(l>>5)*8+j;
    float wv = wih[(size_t)n*512 + k];
    unsigned short hi = f2bf(wv);
    GXWP[i] = hi;
    GXWP[196608 + i] = f2bf(wv - bf2f(hi));
  } else if (blk < 7512){                              // WHH 16x16 A-frags: 49152 items
    int i = (blk-7320)*256 + tid;                      // i = ((g*8+v)*4+kf)*512 + l*8 + j
    int j=i&7, l=(i>>3)&63, kf=(i>>9)&3, v=(i>>11)&7, g=i>>14;
    int m = g*128 + v*16 + (l&15);                     // gate-unit row of whh
    int k = kf*32 + ((l>>4)<<3) + j;
    WHHP[i] = f2bf(whh[(size_t)m*128 + k]);
  } else {                                             // GX bias fold: bih + bhh (r,z only)
    int i = (blk-7512)*256 + tid;
    if (i < 384) GXB[i] = bih[i] + (i < 256 ? bhh[i] : 0.0f);
  }
}

// ============ conv1 (MFMA): x[.,1,84,84] -> 8x8 s4 + relu -> A1[nloc][400 pos][32 ic] bf16
__global__ __launch_bounds__(256) void k_conv1(const float* __restrict__ x,
    const unsigned short* __restrict__ w1p, const float* __restrict__ b,
    unsigned short* __restrict__ a1, int nbase)
{
  __shared__ __align__(16) char imgs[4*14784];     // 4 x [84 rows][88 cols] bf16
  const int tid=threadIdx.x, l=tid&63, w=tid>>6;
  const int nloc = blockIdx.x*4 + w;
  char* myimg = imgs + w*14784;
  const float* xp = x + (size_t)(nbase+nloc)*7056;

  for (int it=0; it<28; ++it){
    int idx4 = l + it*64;                          // over 1764 float4s
    if (idx4 < 1764){
      float4 v = *(const float4*)(xp + idx4*4);
      int row = idx4/21, rem = idx4 - row*21;
      ushort4 u; u.x=f2bf(v.x); u.y=f2bf(v.y); u.z=f2bf(v.z); u.w=f2bf(v.w);
      *(ushort4*)(myimg + row*176 + rem*8) = u;
    }
  }

  bf16x8 wb[4];
  #pragma unroll
  for (int kk=0;kk<4;kk++) wb[kk] = *(const bf16x8*)(w1p + (kk*64 + l)*8);
  const float bias = b[l&31];
  asm volatile("s_waitcnt lgkmcnt(0)" ::: "memory");   // staging ds_writes drained

  const int kyh = (l>>5);
  unsigned short* obase = a1 + (size_t)nloc*12800;
  for (int mt=0; mt<13; ++mt){
    int p = mt*32 + (l&31);
    p = min(p, 399);
    const int oy = p/20, ox = p - oy*20;
    const int rbyte = oy*4*176 + ox*8;
    f32x16 acc = {};
    #pragma unroll
    for (int kk=0;kk<4;kk++){
      const int a = rbyte + (kk*2 + kyh)*176;
      bf16x8 af;
      *(bf16x4*)&af       = *(const bf16x4*)(myimg + a);
      *((bf16x4*)&af + 1) = *(const bf16x4*)(myimg + a + 8);
      acc = mfma32(af, wb[kk], acc);
    }
    const int oc = l&31;
    #pragma unroll
    for (int rg=0;rg<16;rg++){
      int row = (rg&3) + 8*(rg>>2) + 4*kyh;
      int pos = mt*32 + row;
      if (pos < 400)
        obase[pos*32 + oc] = f2bf(fmaxf(acc[rg] + bias, 0.f));
    }
  }
}

// ============ conv2: A1[nloc][400][32] -> 4x4 s2 + relu -> A2[nbase+nloc][81][64] (MFMA)
__global__ __launch_bounds__(256) void k_conv2(const unsigned short* __restrict__ a1,
    const unsigned short* __restrict__ w2p, const float* __restrict__ b2,
    unsigned short* __restrict__ a2, int nbase)
{
  extern __shared__ __align__(16) char smem[];   // 4*25600
  const int tid=threadIdx.x, l=tid&63, w=tid>>6;
  const int nloc = blockIdx.x*4 + w;
  char* myimg = smem + w*25600;
  const char* gimg = (const char*)(a1 + (size_t)nloc*12800);
  #pragma unroll
  for (int i=0;i<25;i++){
    int o = i*1024 + l*16;
    int q = o ^ (((o>>7)&7)<<4);
    gld_lds16(gimg + q, myimg + i*1024);
  }
  __syncthreads();
  int rbase[3];
  #pragma unroll
  for (int mt=0;mt<3;mt++){
    int r = mt*32 + (l&31);
    int oy=r/9, ox=r-oy*9;
    rbase[mt] = 40*oy + 2*ox;
  }
  const int grp16 = (l>>5)*16;
  f32x16 acc[3][2] = {};
  #pragma unroll
  for (int ky=0;ky<4;ky++){
    #pragma unroll
    for (int kx=0;kx<4;kx++){
      const int s = ky*4+kx;
      #pragma unroll
      for (int kh=0;kh<2;kh++){
        bf16x8 b0 = *(const bf16x8*)(w2p + (((s*2+kh)*2+0)*64 + l)*8);
        bf16x8 b1 = *(const bf16x8*)(w2p + (((s*2+kh)*2+1)*64 + l)*8);
        #pragma unroll
        for (int mt=0;mt<3;mt++){
          int ip = rbase[mt] + ky*20 + kx;
          ip = min(ip, 399);
          int byte = (ip*64 + kh*32 + grp16) ^ (((ip>>1)&7)<<4);
          bf16x8 af = *(const bf16x8*)(myimg + byte);
          acc[mt][0] = mfma32(af, b0, acc[mt][0]);
          acc[mt][1] = mfma32(af, b1, acc[mt][1]);
        }
      }
    }
  }
  const float bias0 = b2[l&31], bias1 = b2[32+(l&31)];
  unsigned short* ob = (unsigned short*)myimg;
  #pragma unroll
  for (int mt=0;mt<3;mt++){
    #pragma unroll
    for (int rg=0;rg<16;rg++){
      int r = mt*32 + (rg&3) + 8*(rg>>2) + 4*(l>>5);
      ob[r*64 + (l&31)]      = f2bf(fmaxf(acc[mt][0][rg]+bias0,0.f));
      ob[r*64 + 32 + (l&31)] = f2bf(fmaxf(acc[mt][1][rg]+bias1,0.f));
    }
  }
  asm volatile("s_waitcnt lgkmcnt(0)" ::: "memory");
  const uint4* s4 = (const uint4*)ob;
  uint4* d4 = (uint4*)(a2 + (size_t)(nbase+nloc)*5184);
  #pragma unroll
  for (int i=0;i<11;i++){
    int c = i*64 + l;
    if (c < 648) d4[c] = s4[c];
  }
}

// ============ conv3: A2[n][81][64] -> 3x3 s1 + relu -> A3[n][49][64] bf16 (MFMA)
__global__ __launch_bounds__(256) void k_conv3(const unsigned short* __restrict__ a2,
    const unsigned short* __restrict__ w3p, const float* __restrict__ b3,
    unsigned short* __restrict__ a3)
{
  __shared__ __align__(16) char smem3[4*11264];
  const int tid=threadIdx.x, l=tid&63, w=tid>>6;
  const int n = blockIdx.x*4 + w;
  char* myimg = smem3 + w*11264;
  const char* gimg = (const char*)(a2 + (size_t)n*5184);
  #pragma unroll
  for (int i=0;i<11;i++){
    int c = i*64 + l;
    int cc = min(c, 647);
    int o = cc*16;
    int q = o ^ (((o>>7)&7)<<4);
    gld_lds16(gimg + q, myimg + i*1024);
  }
  __syncthreads();
  int base[2];
  #pragma unroll
  for (int mt=0;mt<2;mt++){
    int r = mt*32 + (l&31);
    int oy=r/7, ox=r-oy*7;
    base[mt] = oy*9 + ox;
  }
  const int grp16 = (l>>5)*16;
  f32x16 acc[2][2] = {};
  #pragma unroll
  for (int ky=0;ky<3;ky++){
    #pragma unroll
    for (int kx=0;kx<3;kx++){
      const int s = ky*3+kx;
      #pragma unroll
      for (int kh=0;kh<4;kh++){
        bf16x8 b0 = *(const bf16x8*)(w3p + (((s*4+kh)*2+0)*64 + l)*8);
        bf16x8 b1 = *(const bf16x8*)(w3p + (((s*4+kh)*2+1)*64 + l)*8);
        #pragma unroll
        for (int mt=0;mt<2;mt++){
          int ip = min(base[mt] + ky*9 + kx, 80);
          int byte = (ip*128 + kh*32 + grp16) ^ ((ip&7)<<4);
          bf16x8 af = *(const bf16x8*)(myimg + byte);
          acc[mt][0] = mfma32(af, b0, acc[mt][0]);
          acc[mt][1] = mfma32(af, b1, acc[mt][1]);
        }
      }
    }
  }
  const float bias0 = b3[l&31], bias1 = b3[32+(l&31)];
  unsigned short* ob = (unsigned short*)myimg;
  #pragma unroll
  for (int mt=0;mt<2;mt++){
    #pragma unroll
    for (int rg=0;rg<16;rg++){
      int r = mt*32 + (rg&3) + 8*(rg>>2) + 4*(l>>5);
      if (r < 49){
        ob[r*64 + (l&31)]      = f2bf(fmaxf(acc[mt][0][rg]+bias0,0.f));
        ob[r*64 + 32 + (l&31)] = f2bf(fmaxf(acc[mt][1][rg]+bias1,0.f));
      }
    }
  }
  asm volatile("s_waitcnt lgkmcnt(0)" ::: "memory");
  const uint4* s4 = (const uint4*)ob;
  uint4* d4 = (uint4*)(a3 + (size_t)n*3136);
  #pragma unroll
  for (int i=0;i<7;i++){
    int c = i*64 + l;
    if (c < 392) d4[c] = s4[c];
  }
}

// ============ GEMM: out[M,N] = act(A[M,K](bf16) @ W^frag + bias) ; BM=128 BN=64 BK=32
// HILO: lo-residual MFMAs. TRGX: write fp32 transposed [t][col][b] with t=r>>5, b=r&31.
template<bool RELU, bool OBF16, bool HILO, bool TRGX>
__global__ __launch_bounds__(256) void k_gemm(const unsigned short* __restrict__ A, int K,
    const unsigned short* __restrict__ Wp, int loOff, const float* __restrict__ bias,
    void* __restrict__ out, int N)
{
  __shared__ __align__(16) char ab[2][8192];
  const int tid=threadIdx.x, l=tid&63, w=tid>>6;
  const int m0=blockIdx.y*128, n0=blockIdx.x*64;
  const int KS=K>>4, T=K>>5;
  const int mh=w&1, ntl=w>>1;
  const int ntg = blockIdx.x*2 + ntl;
  const char* Ab = (const char*)A;

  f32x16 acc[2] = {};
  bf16x8 bh0, bh1, bl0, bl1, nh0, nh1, nl0, nl1;

  #pragma unroll
  for (int i=0;i<2;i++){
    int o = (w*2+i)*1024 + l*16;
    int q = o ^ (((o>>7)&7)<<4);
    int row = q>>6, kc=(q>>4)&3;
    gld_lds16(Ab + ((size_t)(m0+row)*K)*2 + kc*16, ab[0] + (w*2+i)*1024);
  }
  {
    const unsigned short* p0 = Wp + ((size_t)(ntg*KS)*64 + l)*8;
    bh0 = *(const bf16x8*)(p0);
    bh1 = *(const bf16x8*)(p0 + 512);
    if (HILO){
      bl0 = *(const bf16x8*)(p0 + loOff);
      bl1 = *(const bf16x8*)(p0 + loOff + 512);
    }
  }
  __syncthreads();

  for (int t=0;t<T;t++){
    const int cb = t&1;
    if (t+1 < T){
      #pragma unroll
      for (int i=0;i<2;i++){
        int o = (w*2+i)*1024 + l*16;
        int q = o ^ (((o>>7)&7)<<4);
        int row = q>>6, kc=(q>>4)&3;
        gld_lds16(Ab + ((size_t)(m0+row)*K + (t+1)*32)*2 + kc*16, ab[cb^1] + (w*2+i)*1024);
      }
      const unsigned short* pn = Wp + ((size_t)(ntg*KS + (t+1)*2)*64 + l)*8;
      nh0 = *(const bf16x8*)(pn);
      nh1 = *(const bf16x8*)(pn + 512);
      if (HILO){
        nl0 = *(const bf16x8*)(pn + loOff);
        nl1 = *(const bf16x8*)(pn + loOff + 512);
      }
    }
    #pragma unroll
    for (int mt=0;mt<2;mt++){
      int r = mh*64 + mt*32 + (l&31);
      int b0 = (r*64 + (l>>5)*16) ^ (((r>>1)&7)<<4);
      bf16x8 a0 = *(const bf16x8*)(ab[cb] + b0);
      bf16x8 a1 = *(const bf16x8*)(ab[cb] + (b0^32));
      acc[mt] = mfma32(a0, bh0, acc[mt]);
      acc[mt] = mfma32(a1, bh1, acc[mt]);
      if (HILO){
        acc[mt] = mfma32(a0, bl0, acc[mt]);
        acc[mt] = mfma32(a1, bl1, acc[mt]);
      }
    }
    __syncthreads();
    bh0=nh0; bh1=nh1;
    if (HILO){ bl0=nl0; bl1=nl1; }
  }

  const int col = n0 + ntl*32 + (l&31);
  const float bv = bias[col];
  #pragma unroll
  for (int mt=0;mt<2;mt++){
    #pragma unroll
    for (int rg=0;rg<16;rg++){
      int r = m0 + mh*64 + mt*32 + (rg&3) + 8*(rg>>2) + 4*(l>>5);
      float v = acc[mt][rg] + bv;
      if (RELU) v = fmaxf(v, 0.f);
      if (TRGX)       ((float*)out)[(size_t)(r>>5)*12288 + (size_t)col*32 + (r&31)] = v;
      else if (OBF16) ((unsigned short*)out)[(size_t)r*N + col] = f2bf(v);
      else            ((float*)out)[(size_t)r*N + col] = v;
    }
  }
}

// ============ GRU scan v8: ONE block, 8 waves; wave = unit-block v (0..7).
// Fixes vs v7 (471us): (1) __launch_bounds__(512,2) -> VGPR cap 256, wf stays resident
// (v7's VGPR=72 forced spill-reload of 48-reg W-fragments every step);
// (2) gx read from TRANSPOSED GXT[t][384 u][32 b] -> 24 coalesced dword loads;
// (3) hid written as bf16, coalesced from LDS (512 x 16B per step), heads reads bf16.
__global__ __launch_bounds__(512, 2) void k_gru_mfma(const float* __restrict__ gxt,
    const float* __restrict__ done, const float* __restrict__ h0,
    const unsigned short* __restrict__ whhp, const float* __restrict__ bhh,
    unsigned short* __restrict__ hidb, float* __restrict__ hfin)
{
  __shared__ __align__(16) char hsb[2*8448];       // 2 x [32 b][132 u] bf16 (264B rows)
  const int tid = threadIdx.x, l = tid&63, v = tid>>6;   // v = wave = unit-block 0..7
  const int bl = l&15;
  const int u0 = v*16 + ((l>>4)<<2);

  bf16x8 wf[12];                                   // A-frags: 3 gates x 4 K-frags (resident)
  #pragma unroll
  for (int g=0; g<3; ++g)
    #pragma unroll
    for (int kf=0; kf<4; ++kf)
      wf[g*4+kf] = *(const bf16x8*)(whhp + (size_t)(((g*8+v)*4+kf)*64 + l)*8);

  float bn4[4];
  #pragma unroll
  for (int i=0;i<4;i++) bn4[i] = bhh[256 + u0 + i];

  float hp[2][4];
  #pragma unroll
  for (int h=0; h<2; ++h){
    const int b = h*16 + bl;
    float4 h4 = *(const float4*)(h0 + (size_t)b*128 + u0);
    hp[h][0]=h4.x; hp[h][1]=h4.y; hp[h][2]=h4.z; hp[h][3]=h4.w;
    uint2 pk;
    pk.x = (unsigned)f2bf(h4.x) | ((unsigned)f2bf(h4.y)<<16);
    pk.y = (unsigned)f2bf(h4.z) | ((unsigned)f2bf(h4.w)<<16);
    *(uint2*)(hsb + b*264 + u0*2) = pk;
  }

  // prefetch t=0: pg[(h*3+g)*4+i] = GXT[0][g*128+u0+i][b]  (coalesced over bl)
  float pg[24]; float pd[2];
  #pragma unroll
  for (int h=0; h<2; ++h){
    const int b = h*16 + bl;
    #pragma unroll
    for (int g=0; g<3; ++g)
      #pragma unroll
      for (int i=0; i<4; ++i)
        pg[(h*3+g)*4+i] = gxt[(size_t)(g*128+u0+i)*32 + b];
    pd[h] = done[b];
  }
  __syncthreads();

  for (int t=0; t<128; ++t){
    const char* hc = hsb + (t&1)*8448;
    char* hnx = hsb + ((t+1)&1)*8448;
    float cur[24]; float cd[2];
    #pragma unroll
    for (int j=0;j<24;++j) cur[j]=pg[j];
    cd[0]=pd[0]; cd[1]=pd[1];
    if (t+1 < 128){
      const size_t tb = (size_t)(t+1)*12288;
      #pragma unroll
      for (int h=0; h<2; ++h){
        const int b = h*16 + bl;
        #pragma unroll
        for (int g=0; g<3; ++g)
          #pragma unroll
          for (int i=0; i<4; ++i)
            pg[(h*3+g)*4+i] = gxt[tb + (size_t)(g*128+u0+i)*32 + b];
        pd[h] = done[(t+1)*32+b];
      }
    }
    f32x4 acc[2][3] = {};
    #pragma unroll
    for (int h=0; h<2; ++h){
      const int b = h*16 + bl;
      #pragma unroll
      for (int kf=0; kf<4; ++kf){
        bf16x8 hb = *(const bf16x8*)(hc + b*264 + kf*64 + ((l>>4)<<4));
        acc[h][0] = mfma16(wf[kf],   hb, acc[h][0]);
        acc[h][1] = mfma16(wf[4+kf], hb, acc[h][1]);
        acc[h][2] = mfma16(wf[8+kf], hb, acc[h][2]);
      }
    }
    #pragma unroll
    for (int h=0; h<2; ++h){
      const int b = h*16 + bl;
      const float keep = 1.0f - cd[h];
      float hn[4];
      #pragma unroll
      for (int i=0;i<4;i++){
        const float r  = sigmoidf_(cur[(h*3+0)*4+i] + keep*acc[h][0][i]);
        const float z  = sigmoidf_(cur[(h*3+1)*4+i] + keep*acc[h][1][i]);
        const float nn = tanhf_  (cur[(h*3+2)*4+i] + r*(keep*acc[h][2][i] + bn4[i]));
        hn[i] = (1.0f - z)*nn + z*(keep*hp[h][i]);
        hp[h][i] = hn[i];
      }
      uint2 pk;
      pk.x = (unsigned)f2bf(hn[0]) | ((unsigned)f2bf(hn[1])<<16);
      pk.y = (unsigned)f2bf(hn[2]) | ((unsigned)f2bf(hn[3])<<16);
      *(uint2*)(hnx + b*264 + u0*2) = pk;
    }
    asm volatile("s_waitcnt lgkmcnt(0)\n\ts_barrier" ::: "memory");
    __builtin_amdgcn_sched_barrier(0);
    // coalesced hid copy for step t: 512 threads x 16B = 32x128 bf16
    {
      const int row = tid>>4, ch = tid&15;
      uint4 hv = *(const uint4*)(hnx + row*264 + ch*16);
      *(uint4*)(hidb + (size_t)t*4096 + tid*8) = hv;
    }
  }
  #pragma unroll
  for (int h=0; h<2; ++h){
    const int b = h*16 + bl;
    *(float4*)(hfin + (size_t)b*128 + u0) = float4{hp[h][0],hp[h][1],hp[h][2],hp[h][3]};
  }
}

// ============ heads: logits[4096,6], value[4096] ; hid is bf16 [n][128]
__global__ __launch_bounds__(256) void k_heads(const unsigned short* __restrict__ hidb,
    const float* __restrict__ aw, const float* __restrict__ ab,
    const float* __restrict__ cw, const float* __restrict__ cb,
    float* __restrict__ out)
{
  __shared__ __align__(16) float wsm[7*128];
  __shared__ float bb[7];
  const int tid = threadIdx.x;
  for (int i=tid;i<896;i+=256) wsm[i] = (i<768) ? aw[i] : cw[i-768];
  if (tid<7) bb[tid] = (tid<6) ? ab[tid] : cb[0];
  __syncthreads();
  const int idx = blockIdx.x*256 + tid;    // < 28672 exactly
  const int n = idx/7, a = idx - n*7;
  const uint4* hp4 = (const uint4*)(hidb + (size_t)n*128);
  const float* wp = &wsm[a*128];
  float s = bb[a];
  #pragma unroll
  for (int q=0;q<16;q++){
    const uint4 hv = hp4[q];
    const float4 w0 = *(const float4*)(wp + q*8);
    const float4 w1 = *(const float4*)(wp + q*8 + 4);
    s += bf2f((unsigned short)(hv.x&0xffff))*w0.x + bf2f((unsigned short)(hv.x>>16))*w0.y
       + bf2f((unsigned short)(hv.y&0xffff))*w0.z + bf2f((unsigned short)(hv.y>>16))*w0.w
       + bf2f((unsigned short)(hv.z&0xffff))*w1.x + bf2f((unsigned short)(hv.z>>16))*w1.y
       + bf2f((unsigned short)(hv.w&0xffff))*w1.z + bf2f((unsigned short)(hv.w>>16))*w1.w;
  }
  if (a<6) out[(size_t)n*6+a]=s; else out[24576+n]=s;
}

extern "C" void kernel_launch(void* const* d_in, const int* in_sizes, int n_in,
                              void* d_out, int out_size, void* d_ws, size_t ws_size,
                              hipStream_t stream)
{
  const float* x    = (const float*)d_in[0];
  const float* done = (const float*)d_in[1];
  const float* h0   = (const float*)d_in[2];
  const float* c1w  = (const float*)d_in[3];
  const float* c1b  = (const float*)d_in[4];
  const float* c2w  = (const float*)d_in[5];
  const float* c2b  = (const float*)d_in[6];
  const float* c3w  = (const float*)d_in[7];
  const float* c3b  = (const float*)d_in[8];
  const float* fcw  = (const float*)d_in[9];
  const float* fcb  = (const float*)d_in[10];
  const float* wih  = (const float*)d_in[11];
  const float* whh  = (const float*)d_in[12];
  const float* bih  = (const float*)d_in[13];
  const float* bhh  = (const float*)d_in[14];
  const float* aw   = (const float*)d_in[15];
  const float* ab   = (const float*)d_in[16];
  const float* cw   = (const float*)d_in[17];
  const float* cb   = (const float*)d_in[18];
  float* out = (float*)d_out;
  char* ws = (char*)d_ws;

  // ---- workspace layout (bytes). LIVE-RANGE AUDIT:
  //  [0, 7352320)           : weight packs (prep -> consumers)            never overwritten
  //  [7352320, 59781120)    : A1 (conv1 p0,p1), then A3 / FEAT / GXT / HIDB (post-A1)
  //  [59781120, 102248448)  : A2
  //  [102248448, 102348288) : WHHP + GXB  (prep -> gru/gemm; nothing writes here)
  unsigned short* W1P  = (unsigned short*)(ws);               // 4096 B
  unsigned short* W2P  = (unsigned short*)(ws + 4096);        // 65536 B
  unsigned short* W3P  = (unsigned short*)(ws + 69632);       // 73728 B
  unsigned short* FCWP = (unsigned short*)(ws + 143360);      // 6422528 B (hi+lo)
  unsigned short* GXWP = (unsigned short*)(ws + 6565888);     // 786432 B (hi+lo)
  unsigned short* A1   = (unsigned short*)(ws + 7352320);
  unsigned short* A2   = (unsigned short*)(ws + 59781120);    // [59781120, 102248448)
  unsigned short* A3   = (unsigned short*)(ws + 7352320);
  unsigned short* FEAT = (unsigned short*)(ws + 33042432);    // 4194304
  float* GXT  = (float*)(ws + 37236736);                      // 6291456 ([128][384][32] f32)
  unsigned short* HIDB = (unsigned short*)(ws + 43528192);    // 1048576 ([128][32][128] bf16)
  unsigned short* WHHP = (unsigned short*)(ws + 102248448);   // 98304 B
  float* GXB  = (float*)(ws + 102346752);                     // 1536 B

  static bool attr_set = false;
  if (!attr_set) {
    (void)hipFuncSetAttribute((const void*)k_conv2, hipFuncAttributeMaxDynamicSharedMemorySize, 102400);
    attr_set = true;
  }

  k_prep_all<<<7514, 256, 0, stream>>>(c1w, c2w, c3w, fcw, wih, whh, bih, bhh,
                                       W1P, W2P, W3P, FCWP, GXWP, WHHP, GXB);

  for (int pass=0; pass<2; pass++){
    k_conv1<<<512, 256, 0, stream>>>(x, W1P, c1b, A1, pass*2048);
    k_conv2<<<512, 256, 102400, stream>>>(A1, W2P, c2b, A2, pass*2048);
  }
  k_conv3<<<1024, 256, 0, stream>>>(A2, W3P, c3b, A3);
  k_gemm<true, true, false, false><<<dim3(8,32), 256, 0, stream>>>(A3, 3136, FCWP, 0, fcb, (void*)FEAT, 512);
  k_gemm<false,false,true, true ><<<dim3(6,32), 256, 0, stream>>>(FEAT, 512, GXWP, 196608, GXB, (void*)GXT, 384);
  k_gru_mfma<<<1, 512, 0, stream>>>(GXT, done, h0, WHHP, bhh, HIDB, out + 28672);
  k_heads<<<112, 256, 0, stream>>>(HIDB, aw, ab, cw, cb, out);
}

// Round 15
// 337.042 us; speedup vs baseline: 2.0862x; 2.0145x over previous
//
#include <hip/hip_runtime.h>
#include <hip/hip_bf16.h>
#include <stdint.h>

#define DI __device__ __forceinline__

typedef __bf16 bf16x8 __attribute__((ext_vector_type(8)));
typedef __bf16 bf16x4 __attribute__((ext_vector_type(4)));
typedef float f32x16 __attribute__((ext_vector_type(16)));
typedef float f32x2 __attribute__((ext_vector_type(2)));

DI float bf2f(unsigned short u){ return __uint_as_float(((unsigned int)u)<<16); }
DI unsigned short f2bf(float f){
  unsigned int x = __float_as_uint(f);
  x += 0x7fffu + ((x>>16)&1u);           // RNE; inputs are finite
  return (unsigned short)(x>>16);
}
DI float sigmoidf_(float x){ return 1.0f/(1.0f + __expf(-x)); }
DI float tanhf_(float x){ return 2.0f/(1.0f + __expf(-2.0f*x)) - 1.0f; }  // NaN-safe at both extremes

DI void gld_lds16(const void* g, void* l){
  __builtin_amdgcn_global_load_lds((const __attribute__((address_space(1))) void*)g,
                                   (__attribute__((address_space(3))) void*)l, 16, 0, 0);
}
DI f32x16 mfma32(bf16x8 a, bf16x8 b, f32x16 c){
  return __builtin_amdgcn_mfma_f32_32x32x16_bf16(a, b, c, 0, 0, 0);
}

// ============ merged weight prep: all packs in ONE kernel ============
// frag layout: [tile-linear][lane 64][j 8]; per frag: col n=(l&31)+32*nt, k=(l>>5)*8+j
__global__ __launch_bounds__(256) void k_prep_all(
    const float* __restrict__ w1, const float* __restrict__ w2, const float* __restrict__ w3,
    const float* __restrict__ fcw, const float* __restrict__ wih,
    unsigned short* __restrict__ W1P, unsigned short* __restrict__ W2P,
    unsigned short* __restrict__ W3P, unsigned short* __restrict__ FCWP,
    unsigned short* __restrict__ GXWP)
{
  const int blk = blockIdx.x, tid = threadIdx.x;
  if (blk < 8){                                        // conv1: 2048 = 4 kk * 512, /255 folded
    int idx = blk*256 + tid;
    int j=idx&7, l=(idx>>3)&63, kk=idx>>9;
    int oc=l&31, kg=kk*16+((l>>5)<<3)+j;
    W1P[idx] = f2bf(w1[oc*64 + kg] * (1.0f/255.0f));
  } else if (blk < 136){                               // conv2: 32768 = 16 s * 2 kh * 2 nt * 512
    int idx = (blk-8)*256 + tid;
    int j=idx&7, l=(idx>>3)&63, nt=(idx>>9)&1, kh=(idx>>10)&1, s=idx>>11;
    int oc=nt*32+(l&31), ic=kh*16+(l>>5)*8+j, ky=s>>2, kx=s&3;
    W2P[idx] = f2bf(w2[((oc*32+ic)*4+ky)*4+kx]);
  } else if (blk < 280){                               // conv3: 36864 = 9 s * 4 kh * 2 nt * 512
    int idx = (blk-136)*256 + tid;
    int j=idx&7, l=(idx>>3)&63, nt=(idx>>9)&1, kh=(idx>>10)&3, s=idx>>12;
    int oc=nt*32+(l&31), ic=kh*16+(l>>5)*8+j, ky=s/3, kx=s-ky*3;
    W3P[idx] = f2bf(w3[((oc*64+ic)*3+ky)*3+kx]);
  } else if (blk < 6552){                              // FC: 1605632 items; A3 k'=pos*64+c
    int i = (blk-280)*256 + tid;
    int t2 = i&511, rest = i>>9;
    int ks = rest%196, nt = rest/196;
    int j=t2&7, l=t2>>3;
    int n=nt*32+(l&31), k=ks*16+(l>>5)*8+j;
    int c=k&63, pos=k>>6;
    float wv = fcw[(size_t)n*3136 + c*49 + pos];
    unsigned short hi = f2bf(wv);
    FCWP[i] = hi;
    FCWP[1605632 + i] = f2bf(wv - bf2f(hi));           // lo kept (FC runs hi-only; harmless)
  } else {                                             // GX: 196608 items, hi+lo
    int i = (blk-6552)*256 + tid;
    int t2 = i&511, rest = i>>9;
    int ks = rest&31, nt = rest>>5;
    int j=t2&7, l=t2>>3;
    int n=nt*32+(l&31), k=ks*16+(l>>5)*8+j;
    float wv = wih[(size_t)n*512 + k];
    unsigned short hi = f2bf(wv);
    GXWP[i] = hi;
    GXWP[196608 + i] = f2bf(wv - bf2f(hi));
  }
}

// ============ conv1 (MFMA): x[.,1,84,84] -> 8x8 s4 + relu -> A1[nloc][400 pos][32 ic] bf16
__global__ __launch_bounds__(256) void k_conv1(const float* __restrict__ x,
    const unsigned short* __restrict__ w1p, const float* __restrict__ b,
    unsigned short* __restrict__ a1, int nbase)
{
  __shared__ __align__(16) char imgs[4*14784];     // 4 x [84 rows][88 cols] bf16
  const int tid=threadIdx.x, l=tid&63, w=tid>>6;
  const int nloc = blockIdx.x*4 + w;
  char* myimg = imgs + w*14784;
  const float* xp = x + (size_t)(nbase+nloc)*7056;

  for (int it=0; it<28; ++it){
    int idx4 = l + it*64;                          // over 1764 float4s
    if (idx4 < 1764){
      float4 v = *(const float4*)(xp + idx4*4);
      int row = idx4/21, rem = idx4 - row*21;
      ushort4 u; u.x=f2bf(v.x); u.y=f2bf(v.y); u.z=f2bf(v.z); u.w=f2bf(v.w);
      *(ushort4*)(myimg + row*176 + rem*8) = u;
    }
  }

  bf16x8 wb[4];
  #pragma unroll
  for (int kk=0;kk<4;kk++) wb[kk] = *(const bf16x8*)(w1p + (kk*64 + l)*8);
  const float bias = b[l&31];
  asm volatile("s_waitcnt lgkmcnt(0)" ::: "memory");   // staging ds_writes drained

  const int kyh = (l>>5);
  unsigned short* obase = a1 + (size_t)nloc*12800;
  for (int mt=0; mt<13; ++mt){
    int p = mt*32 + (l&31);
    p = min(p, 399);
    const int oy = p/20, ox = p - oy*20;
    const int rbyte = oy*4*176 + ox*8;
    f32x16 acc = {};
    #pragma unroll
    for (int kk=0;kk<4;kk++){
      const int a = rbyte + (kk*2 + kyh)*176;
      bf16x8 af;
      *(bf16x4*)&af       = *(const bf16x4*)(myimg + a);
      *((bf16x4*)&af + 1) = *(const bf16x4*)(myimg + a + 8);
      acc = mfma32(af, wb[kk], acc);
    }
    const int oc = l&31;
    #pragma unroll
    for (int rg=0;rg<16;rg++){
      int row = (rg&3) + 8*(rg>>2) + 4*kyh;
      int pos = mt*32 + row;
      if (pos < 400)
        obase[pos*32 + oc] = f2bf(fmaxf(acc[rg] + bias, 0.f));
    }
  }
}

// ============ conv2: A1[nloc][400][32] -> 4x4 s2 + relu -> A2[nbase+nloc][81][64] (MFMA)
__global__ __launch_bounds__(256) void k_conv2(const unsigned short* __restrict__ a1,
    const unsigned short* __restrict__ w2p, const float* __restrict__ b2,
    unsigned short* __restrict__ a2, int nbase)
{
  extern __shared__ __align__(16) char smem[];   // 4*25600
  const int tid=threadIdx.x, l=tid&63, w=tid>>6;
  const int nloc = blockIdx.x*4 + w;
  char* myimg = smem + w*25600;
  const char* gimg = (const char*)(a1 + (size_t)nloc*12800);
  #pragma unroll
  for (int i=0;i<25;i++){
    int o = i*1024 + l*16;
    int q = o ^ (((o>>7)&7)<<4);
    gld_lds16(gimg + q, myimg + i*1024);
  }
  __syncthreads();
  int rbase[3];
  #pragma unroll
  for (int mt=0;mt<3;mt++){
    int r = mt*32 + (l&31);
    int oy=r/9, ox=r-oy*9;
    rbase[mt] = 40*oy + 2*ox;
  }
  const int grp16 = (l>>5)*16;
  f32x16 acc[3][2] = {};
  #pragma unroll
  for (int ky=0;ky<4;ky++){
    #pragma unroll
    for (int kx=0;kx<4;kx++){
      const int s = ky*4+kx;
      #pragma unroll
      for (int kh=0;kh<2;kh++){
        bf16x8 b0 = *(const bf16x8*)(w2p + (((s*2+kh)*2+0)*64 + l)*8);
        bf16x8 b1 = *(const bf16x8*)(w2p + (((s*2+kh)*2+1)*64 + l)*8);
        #pragma unroll
        for (int mt=0;mt<3;mt++){
          int ip = rbase[mt] + ky*20 + kx;
          ip = min(ip, 399);
          int byte = (ip*64 + kh*32 + grp16) ^ (((ip>>1)&7)<<4);
          bf16x8 af = *(const bf16x8*)(myimg + byte);
          acc[mt][0] = mfma32(af, b0, acc[mt][0]);
          acc[mt][1] = mfma32(af, b1, acc[mt][1]);
        }
      }
    }
  }
  const float bias0 = b2[l&31], bias1 = b2[32+(l&31)];
  unsigned short* ob = (unsigned short*)myimg;
  #pragma unroll
  for (int mt=0;mt<3;mt++){
    #pragma unroll
    for (int rg=0;rg<16;rg++){
      int r = mt*32 + (rg&3) + 8*(rg>>2) + 4*(l>>5);
      ob[r*64 + (l&31)]      = f2bf(fmaxf(acc[mt][0][rg]+bias0,0.f));
      ob[r*64 + 32 + (l&31)] = f2bf(fmaxf(acc[mt][1][rg]+bias1,0.f));
    }
  }
  asm volatile("s_waitcnt lgkmcnt(0)" ::: "memory");
  const uint4* s4 = (const uint4*)ob;
  uint4* d4 = (uint4*)(a2 + (size_t)(nbase+nloc)*5184);
  #pragma unroll
  for (int i=0;i<11;i++){
    int c = i*64 + l;
    if (c < 648) d4[c] = s4[c];
  }
}

// ============ conv3: A2[n][81][64] -> 3x3 s1 + relu -> A3[n][49][64] bf16 (MFMA)
__global__ __launch_bounds__(256) void k_conv3(const unsigned short* __restrict__ a2,
    const unsigned short* __restrict__ w3p, const float* __restrict__ b3,
    unsigned short* __restrict__ a3)
{
  __shared__ __align__(16) char smem3[4*11264];
  const int tid=threadIdx.x, l=tid&63, w=tid>>6;
  const int n = blockIdx.x*4 + w;
  char* myimg = smem3 + w*11264;
  const char* gimg = (const char*)(a2 + (size_t)n*5184);
  #pragma unroll
  for (int i=0;i<11;i++){
    int c = i*64 + l;
    int cc = min(c, 647);
    int o = cc*16;
    int q = o ^ (((o>>7)&7)<<4);
    gld_lds16(gimg + q, myimg + i*1024);
  }
  __syncthreads();
  int base[2];
  #pragma unroll
  for (int mt=0;mt<2;mt++){
    int r = mt*32 + (l&31);
    int oy=r/7, ox=r-oy*7;
    base[mt] = oy*9 + ox;
  }
  const int grp16 = (l>>5)*16;
  f32x16 acc[2][2] = {};
  #pragma unroll
  for (int ky=0;ky<3;ky++){
    #pragma unroll
    for (int kx=0;kx<3;kx++){
      const int s = ky*3+kx;
      #pragma unroll
      for (int kh=0;kh<4;kh++){
        bf16x8 b0 = *(const bf16x8*)(w3p + (((s*4+kh)*2+0)*64 + l)*8);
        bf16x8 b1 = *(const bf16x8*)(w3p + (((s*4+kh)*2+1)*64 + l)*8);
        #pragma unroll
        for (int mt=0;mt<2;mt++){
          int ip = min(base[mt] + ky*9 + kx, 80);
          int byte = (ip*128 + kh*32 + grp16) ^ ((ip&7)<<4);
          bf16x8 af = *(const bf16x8*)(myimg + byte);
          acc[mt][0] = mfma32(af, b0, acc[mt][0]);
          acc[mt][1] = mfma32(af, b1, acc[mt][1]);
        }
      }
    }
  }
  const float bias0 = b3[l&31], bias1 = b3[32+(l&31)];
  unsigned short* ob = (unsigned short*)myimg;
  #pragma unroll
  for (int mt=0;mt<2;mt++){
    #pragma unroll
    for (int rg=0;rg<16;rg++){
      int r = mt*32 + (rg&3) + 8*(rg>>2) + 4*(l>>5);
      if (r < 49){
        ob[r*64 + (l&31)]      = f2bf(fmaxf(acc[mt][0][rg]+bias0,0.f));
        ob[r*64 + 32 + (l&31)] = f2bf(fmaxf(acc[mt][1][rg]+bias1,0.f));
      }
    }
  }
  asm volatile("s_waitcnt lgkmcnt(0)" ::: "memory");
  const uint4* s4 = (const uint4*)ob;
  uint4* d4 = (uint4*)(a3 + (size_t)n*3136);
  #pragma unroll
  for (int i=0;i<7;i++){
    int c = i*64 + l;
    if (c < 392) d4[c] = s4[c];
  }
}

// ============ GEMM: out[M,N] = act(A[M,K](bf16) @ W^frag + bias) ; BM=128 BN=64 BK=32
template<bool RELU, bool OBF16, bool HILO>
__global__ __launch_bounds__(256) void k_gemm(const unsigned short* __restrict__ A, int K,
    const unsigned short* __restrict__ Wp, int loOff, const float* __restrict__ bias,
    void* __restrict__ out, int N)
{
  __shared__ __align__(16) char ab[2][8192];
  const int tid=threadIdx.x, l=tid&63, w=tid>>6;
  const int m0=blockIdx.y*128, n0=blockIdx.x*64;
  const int KS=K>>4, T=K>>5;
  const int mh=w&1, ntl=w>>1;
  const int ntg = blockIdx.x*2 + ntl;
  const char* Ab = (const char*)A;

  f32x16 acc[2] = {};
  bf16x8 bh0, bh1, bl0, bl1, nh0, nh1, nl0, nl1;

  #pragma unroll
  for (int i=0;i<2;i++){
    int o = (w*2+i)*1024 + l*16;
    int q = o ^ (((o>>7)&7)<<4);
    int row = q>>6, kc=(q>>4)&3;
    gld_lds16(Ab + ((size_t)(m0+row)*K)*2 + kc*16, ab[0] + (w*2+i)*1024);
  }
  {
    const unsigned short* p0 = Wp + ((size_t)(ntg*KS)*64 + l)*8;
    bh0 = *(const bf16x8*)(p0);
    bh1 = *(const bf16x8*)(p0 + 512);
    if (HILO){
      bl0 = *(const bf16x8*)(p0 + loOff);
      bl1 = *(const bf16x8*)(p0 + loOff + 512);
    }
  }
  __syncthreads();

  for (int t=0;t<T;t++){
    const int cb = t&1;
    if (t+1 < T){
      #pragma unroll
      for (int i=0;i<2;i++){
        int o = (w*2+i)*1024 + l*16;
        int q = o ^ (((o>>7)&7)<<4);
        int row = q>>6, kc=(q>>4)&3;
        gld_lds16(Ab + ((size_t)(m0+row)*K + (t+1)*32)*2 + kc*16, ab[cb^1] + (w*2+i)*1024);
      }
      const unsigned short* pn = Wp + ((size_t)(ntg*KS + (t+1)*2)*64 + l)*8;
      nh0 = *(const bf16x8*)(pn);
      nh1 = *(const bf16x8*)(pn + 512);
      if (HILO){
        nl0 = *(const bf16x8*)(pn + loOff);
        nl1 = *(const bf16x8*)(pn + loOff + 512);
      }
    }
    #pragma unroll
    for (int mt=0;mt<2;mt++){
      int r = mh*64 + mt*32 + (l&31);
      int b0 = (r*64 + (l>>5)*16) ^ (((r>>1)&7)<<4);
      bf16x8 a0 = *(const bf16x8*)(ab[cb] + b0);
      bf16x8 a1 = *(const bf16x8*)(ab[cb] + (b0^32));
      acc[mt] = mfma32(a0, bh0, acc[mt]);
      acc[mt] = mfma32(a1, bh1, acc[mt]);
      if (HILO){
        acc[mt] = mfma32(a0, bl0, acc[mt]);
        acc[mt] = mfma32(a1, bl1, acc[mt]);
      }
    }
    __syncthreads();
    bh0=nh0; bh1=nh1;
    if (HILO){ bl0=nl0; bl1=nl1; }
  }

  const int col = n0 + ntl*32 + (l&31);
  const float bv = bias[col];
  #pragma unroll
  for (int mt=0;mt<2;mt++){
    #pragma unroll
    for (int rg=0;rg<16;rg++){
      int r = m0 + mh*64 + mt*32 + (rg&3) + 8*(rg>>2) + 4*(l>>5);
      float v = acc[mt][rg] + bv;
      if (RELU) v = fmaxf(v, 0.f);
      if (OBF16) ((unsigned short*)out)[(size_t)r*N + col] = f2bf(v);
      else       ((float*)out)[(size_t)r*N + col] = v;
    }
  }
}

// ============ GRU scan v3 (proven 107.7us, R8): one block per batch element;
// 4 threads per hidden unit; stagger in one-time weight load -> static reg indices,
// conflict-free broadcast LDS reads; gx/done prefetch; 1 barrier/step; fast tanh.
__global__ __launch_bounds__(512) void k_gru(const float* __restrict__ gx,
    const float* __restrict__ done, const float* __restrict__ h0,
    const float* __restrict__ whh, const float* __restrict__ bhh,
    float* __restrict__ hid, float* __restrict__ hfin)
{
  __shared__ __align__(16) float hs[2][128];
  const int b = blockIdx.x, tid = threadIdx.x;
  const int u = tid>>2, sub = tid&3;
  f32x2 wr[16], wz[16], wn[16];
  const float* wru = whh + (size_t)u*128 + sub*32;
  const float* wzu = whh + (size_t)(u+128)*128 + sub*32;
  const float* wnu = whh + (size_t)(u+256)*128 + sub*32;
  #pragma unroll
  for (int q=0;q<8;q++){
    const int e = (q + sub*2)&7;                   // runtime SOURCE addr, static DEST index
    float4 a = *(const float4*)(wru + e*4);
    float4 c = *(const float4*)(wzu + e*4);
    float4 d = *(const float4*)(wnu + e*4);
    wr[q*2] = f32x2{a.x,a.y}; wr[q*2+1] = f32x2{a.z,a.w};
    wz[q*2] = f32x2{c.x,c.y}; wz[q*2+1] = f32x2{c.z,c.w};
    wn[q*2] = f32x2{d.x,d.y}; wn[q*2+1] = f32x2{d.z,d.w};
  }
  const float br = bhh[u], bz = bhh[u+128], bn = bhh[u+256];
  if (tid<128) hs[0][tid] = h0[(size_t)b*128+tid];

  // prefetch t=0
  const float* g0 = gx + (size_t)b*384;
  float pg0 = g0[u], pg1 = g0[u+128], pg2 = g0[u+256];
  float pd  = done[b];
  __syncthreads();

  for (int t=0;t<128;t++){
    const int cur = t&1;
    const float gr=pg0, gz=pg1, gn=pg2, dn=pd;
    if (t+1 < 128){
      const float* gp = gx + ((size_t)(t+1)*32+b)*384;
      pg0=gp[u]; pg1=gp[u+128]; pg2=gp[u+256];
      pd = done[(t+1)*32+b];
    }
    const float hpv = hs[cur][u];
    const float* hb = &hs[cur][sub*32];
    f32x2 hv[16];
    #pragma unroll
    for (int q=0;q<8;q++){
      const int e = (q + sub*2)&7;                 // runtime LDS addr, static reg index
      float4 v = *(const float4*)(hb + e*4);
      hv[q*2]   = f32x2{v.x,v.y};
      hv[q*2+1] = f32x2{v.z,v.w};
    }
    f32x2 a2r = {0.f,0.f}, a2z = {0.f,0.f}, a2n = {0.f,0.f};
    #pragma unroll
    for (int i=0;i<16;i++){
      a2r += wr[i]*hv[i];
      a2z += wz[i]*hv[i];
      a2n += wn[i]*hv[i];
    }
    float ar=a2r[0]+a2r[1], az=a2z[0]+a2z[1], an=a2n[0]+a2n[1];
    ar += __shfl_xor(ar,1); ar += __shfl_xor(ar,2);
    az += __shfl_xor(az,1); az += __shfl_xor(az,2);
    an += __shfl_xor(an,1); an += __shfl_xor(an,2);
    if (sub==0){
      const float keep = 1.0f - dn;
      const float hp = keep*hpv;
      const float r  = sigmoidf_(gr + keep*ar + br);
      const float z  = sigmoidf_(gz + keep*az + bz);
      const float nn = tanhf_  (gn + r*(keep*an + bn));
      const float hn = (1.0f-z)*nn + z*hp;
      hs[cur^1][u] = hn;
      hid[((size_t)t*32+b)*128 + u] = hn;
    }
    asm volatile("s_waitcnt lgkmcnt(0)\n\ts_barrier" ::: "memory");
    __builtin_amdgcn_sched_barrier(0);
  }
  if (tid<128) hfin[(size_t)b*128+tid] = hs[0][tid];   // t=127 wrote buffer 0
}

// ============ heads: logits[4096,6], value[4096]
__global__ __launch_bounds__(256) void k_heads(const float* __restrict__ hid,
    const float* __restrict__ aw, const float* __restrict__ ab,
    const float* __restrict__ cw, const float* __restrict__ cb,
    float* __restrict__ out)
{
  __shared__ __align__(16) float wsm[7*128];
  __shared__ float bb[7];
  const int tid = threadIdx.x;
  for (int i=tid;i<896;i+=256) wsm[i] = (i<768) ? aw[i] : cw[i-768];
  if (tid<7) bb[tid] = (tid<6) ? ab[tid] : cb[0];
  __syncthreads();
  const int idx = blockIdx.x*256 + tid;    // < 28672 exactly
  const int n = idx/7, a = idx - n*7;
  const float4* hp = (const float4*)(hid + (size_t)n*128);
  const float4* wp = (const float4*)(&wsm[a*128]);
  float s = bb[a];
  #pragma unroll
  for (int q=0;q<32;q++){
    const float4 h4=hp[q], w4=wp[q];
    s += h4.x*w4.x + h4.y*w4.y + h4.z*w4.z + h4.w*w4.w;
  }
  if (a<6) out[(size_t)n*6+a]=s; else out[24576+n]=s;
}

extern "C" void kernel_launch(void* const* d_in, const int* in_sizes, int n_in,
                              void* d_out, int out_size, void* d_ws, size_t ws_size,
                              hipStream_t stream)
{
  const float* x    = (const float*)d_in[0];
  const float* done = (const float*)d_in[1];
  const float* h0   = (const float*)d_in[2];
  const float* c1w  = (const float*)d_in[3];
  const float* c1b  = (const float*)d_in[4];
  const float* c2w  = (const float*)d_in[5];
  const float* c2b  = (const float*)d_in[6];
  const float* c3w  = (const float*)d_in[7];
  const float* c3b  = (const float*)d_in[8];
  const float* fcw  = (const float*)d_in[9];
  const float* fcb  = (const float*)d_in[10];
  const float* wih  = (const float*)d_in[11];
  const float* whh  = (const float*)d_in[12];
  const float* bih  = (const float*)d_in[13];
  const float* bhh  = (const float*)d_in[14];
  const float* aw   = (const float*)d_in[15];
  const float* ab   = (const float*)d_in[16];
  const float* cw   = (const float*)d_in[17];
  const float* cb   = (const float*)d_in[18];
  float* out = (float*)d_out;
  char* ws = (char*)d_ws;

  // ---- workspace layout (bytes). LIVE-RANGE AUDIT:
  //  [0, 7352320)         : weight packs (prep -> consumers), never overwritten
  //  [7352320, 59781120)  : A1 (conv1 p0,p1) then A3/FEAT/GX/HID (all post-A1-death)
  //  [59781120, 102248448): A2
  unsigned short* W1P  = (unsigned short*)(ws);               // 4096 B
  unsigned short* W2P  = (unsigned short*)(ws + 4096);        // 65536 B
  unsigned short* W3P  = (unsigned short*)(ws + 69632);       // 73728 B
  unsigned short* FCWP = (unsigned short*)(ws + 143360);      // 6422528 B (hi+lo)
  unsigned short* GXWP = (unsigned short*)(ws + 6565888);     // 786432 B (hi+lo)
  unsigned short* A1   = (unsigned short*)(ws + 7352320);
  unsigned short* A2   = (unsigned short*)(ws + 59781120);
  unsigned short* A3   = (unsigned short*)(ws + 7352320);
  unsigned short* FEAT = (unsigned short*)(ws + 33042432);    // 4194304
  float* GX   = (float*)(ws + 37236736);                      // 6291456
  float* HID  = (float*)(ws + 43528192);                      // 2097152

  static bool attr_set = false;
  if (!attr_set) {
    (void)hipFuncSetAttribute((const void*)k_conv2, hipFuncAttributeMaxDynamicSharedMemorySize, 102400);
    attr_set = true;
  }

  k_prep_all<<<7320, 256, 0, stream>>>(c1w, c2w, c3w, fcw, wih, W1P, W2P, W3P, FCWP, GXWP);

  for (int pass=0; pass<2; pass++){
    k_conv1<<<512, 256, 0, stream>>>(x, W1P, c1b, A1, pass*2048);
    k_conv2<<<512, 256, 102400, stream>>>(A1, W2P, c2b, A2, pass*2048);
  }
  k_conv3<<<1024, 256, 0, stream>>>(A2, W3P, c3b, A3);
  k_gemm<true, true, false><<<dim3(8,32), 256, 0, stream>>>(A3, 3136, FCWP, 0, fcb, (void*)FEAT, 512);
  k_gemm<false,false,true ><<<dim3(6,32), 256, 0, stream>>>(FEAT, 512, GXWP, 196608, bih, (void*)GX, 384);
  k_gru<<<32, 512, 0, stream>>>(GX, done, h0, whh, bhh, HID, out + 28672);
  k_heads<<<112, 256, 0, stream>>>(HID, aw, ab, cw, cb, out);
}